// Round 20
// baseline (124.488 us; speedup 1.0000x reference)
//
#include <hip/hip_runtime.h>
#include <math.h>

// Fbank via split-bf16 MFMA + real-DFT folding. R20 = R19 + s_setprio(1)
// around MFMA clusters (T5): waves in a block have role diversity (pack vs
// GEMM phases, waves 0-3 do double pack duty) and 2 blocks/CU drift apart,
// so priority-boosting MFMA-issuing waves can keep the matrix pipe fed.

#define BATCH 32
#define TLEN 480000
#define NFRAMES 2998
#define FL 400
#define FS 160
#define PW 512
#define NM 80
#define MT 48                // frames per block
#define NTILES 63            // ceil(2998/48)
#define PRE 0.97f
#define EPSF 1e-6f

#define RE_KS 9              // K=288 (t 0..256 + pad)
#define IM_KS 8              // K=256 (t 0..255)
#define RE_U16 (16 * RE_KS * 64 * 8)   // 73728
#define IM_U16 (16 * IM_KS * 64 * 8)   // 65536
#define MEL_U16 (6 * 8 * 64 * 8)       // 24576
#define OFF_REH 0
#define OFF_REL RE_U16
#define OFF_IMH (2 * RE_U16)
#define OFF_IML (2 * RE_U16 + IM_U16)
#define OFF_MEL (2 * RE_U16 + 2 * IM_U16)
#define OFF_CS  (OFF_MEL + MEL_U16)          // u16 units; 512 floats follow
#define WS_NEED ((size_t)OFF_CS * 2 + 512 * 4)   // ~608 KB

// LDS tile byte offsets (48 rows). 272-B stride tiles: natural bank rotation,
// no XOR. 320-B chunk1 s-tile: SWT1 XOR (bits 4..5; +8 half-offset is bit 3).
#define C0_SH 0
#define C0_SL 13056
#define C0_DH 26112
#define C0_DL 39168          // chunk0 total 52,224 B
#define C1_SH 0
#define C1_SL 15360
#define C1_DH 30720
#define C1_DL 43776          // chunk1 total 56,832 B

typedef short bf16x8 __attribute__((ext_vector_type(8)));
typedef float f32x4 __attribute__((ext_vector_type(4)));
typedef unsigned int u32;
typedef unsigned short u16;
typedef u32 u32x2 __attribute__((ext_vector_type(2)));

__device__ __forceinline__ u16 f2bf(float f) {
    u32 u = __builtin_bit_cast(u32, f);
    return (u16)((u + 0x7FFFu + ((u >> 16) & 1u)) >> 16);
}
__device__ __forceinline__ float bf2f(u16 h) {
    u32 u = ((u32)h) << 16;
    return __builtin_bit_cast(float, u);
}
// packed bf16 convert: src0 -> low half, src1 -> high half
__device__ __forceinline__ u32 cvtpk2(float lo, float hi) {
    u32 r;
    asm("v_cvt_pk_bf16_f32 %0, %1, %2" : "=v"(r) : "v"(lo), "v"(hi));
    return r;
}

// ---------------- prep: folded B (cos/sin hi+lo) + mel ----------------
__global__ void prep_kernel(const float* __restrict__ dftr, const float* __restrict__ dfti,
                            const float* __restrict__ melw, u16* __restrict__ wsb) {
    int idx = blockIdx.x * 256 + threadIdx.x;
    if (idx < 16 * RE_KS * 64) {                       // 9216 Re groups
        int nf = idx / (RE_KS * 64);
        int rem = idx - nf * (RE_KS * 64);
        int ks = rem >> 6, l = rem & 63;
        int f = nf * 16 + (l & 15);
        int k = ks * 32 + ((l >> 4) << 3);
        u16* dh = wsb + OFF_REH + (size_t)idx * 8;
        u16* dl = wsb + OFF_REL + (size_t)idx * 8;
        #pragma unroll
        for (int e = 0; e < 8; ++e) {
            int kk = k + e;
            float x = (kk <= 256) ? dftr[(size_t)f * PW + kk] : 0.f;
            u16 h = f2bf(x);
            dh[e] = h;
            dl[e] = f2bf(x - bf2f(h));
        }
    } else if (idx < 16 * RE_KS * 64 + 16 * IM_KS * 64) {   // 8192 Im groups
        int j = idx - 16 * RE_KS * 64;
        int nf = j / (IM_KS * 64);
        int rem = j - nf * (IM_KS * 64);
        int ks = rem >> 6, l = rem & 63;
        int f = nf * 16 + (l & 15);
        int k = ks * 32 + ((l >> 4) << 3);
        u16* dh = wsb + OFF_IMH + (size_t)j * 8;
        u16* dl = wsb + OFF_IML + (size_t)j * 8;
        #pragma unroll
        for (int e = 0; e < 8; ++e) {
            float x = dfti[(size_t)f * PW + k + e];    // k+e <= 255
            u16 h = f2bf(x);
            dh[e] = h;
            dl[e] = f2bf(x - bf2f(h));
        }
    } else {                                            // mel groups
        int m = idx - (16 * RE_KS * 64 + 16 * IM_KS * 64);
        if (m < 6 * 8 * 64) {
            int nf = m / (8 * 64);
            int ks = (m >> 6) & 7, l = m & 63;
            int n = nf * 16 + (l & 15);
            int k = ks * 32 + ((l >> 4) << 3);
            u16* dst = wsb + OFF_MEL + (size_t)m * 8;
            #pragma unroll
            for (int e = 0; e < 8; ++e)
                dst[e] = (n < NM) ? f2bf(melw[(size_t)n * 257 + k + e]) : (u16)0;
        }
    }
}

// ---------------- prep C/S: one wave per bin (512 waves) ----------------
__global__ void prep_cs_kernel(const float* __restrict__ dftr, const float* __restrict__ dfti,
                               const float* __restrict__ win, u16* __restrict__ wsb) {
    const int gw = (blockIdx.x * 256 + threadIdx.x) >> 6;   // 0..511
    const int lane = threadIdx.x & 63;
    float* cs = (float*)(wsb + OFF_CS);
    float acc = 0.f;
    if (gw < 256) {
        const int f = gw;
        for (int t = lane; t <= 256; t += 64) {
            float wt = (t < FL) ? win[t] : 0.f;
            float wu = (t >= 1 && t < 256 && (512 - t) < FL) ? win[512 - t] : 0.f;
            acc += (wt + wu) * dftr[(size_t)f * PW + t];
        }
    } else {
        const int ff = gw - 256;
        for (int t = lane; t <= 255; t += 64) {
            float wt = (t < FL) ? win[t] : 0.f;
            float wu = (t >= 1 && (512 - t) < FL) ? win[512 - t] : 0.f;
            acc += (wt - wu) * dfti[(size_t)ff * PW + t];
        }
    }
    #pragma unroll
    for (int o = 32; o; o >>= 1) acc += __shfl_xor(acc, o);
    if (lane == 0) cs[gw] = acc;
}

// swizzle select: 0 -> (r&7)<<4 (512-B stride), 1 -> ((r>>1)&3)<<4 (320-B), 2 -> none (272-B)
__device__ __forceinline__ u32 swz(int SWT, u32 r) {
    return (SWT == 0) ? ((r & 7u) << 4) : (SWT == 1) ? (((r >> 1) & 3u) << 4) : 0u;
}

// 9 MFMA for one (bh,bl) ping-pong slot, setprio-wrapped (T5)
#define MFMA9(D, J)                                                                        \
    __builtin_amdgcn_s_setprio(1);                                                         \
    _Pragma("unroll")                                                                      \
    for (int mf = 0; mf < 3; ++mf) {                                                       \
        acc[mf][J] = __builtin_amdgcn_mfma_f32_16x16x32_bf16(aH[mf], D[0], acc[mf][J], 0, 0, 0); \
        acc[mf][J] = __builtin_amdgcn_mfma_f32_16x16x32_bf16(aL[mf], D[0], acc[mf][J], 0, 0, 0); \
        acc[mf][J] = __builtin_amdgcn_mfma_f32_16x16x32_bf16(aH[mf], D[1], acc[mf][J], 0, 0, 0); \
    }                                                                                      \
    __builtin_amdgcn_s_setprio(0);

// ---------------- DFT pass: 3 m-frags, 2 n-frags, B ping-pong prefetch ----------------
template<int RS, int SWT, int NKS, int BKS>
__device__ __forceinline__ void dft_pass3(
    const char* tH, const char* tL,
    const u16* __restrict__ bH, const u16* __restrict__ bL,
    int ks0, int w, int lane, f32x4 (&acc)[3][2]) {

    bf16x8 aH[3], aL[3], Ba[2], Bb[2];

#define LDA_P(KS)                                                              \
    { _Pragma("unroll")                                                        \
      for (int mf = 0; mf < 3; ++mf) {                                         \
        u32 r = (u32)(mf * 16 + (lane & 15));                                  \
        u32 off = (u32)((KS) * 64 + ((lane >> 4) << 4));                       \
        u32 byte = r * RS + (off ^ swz(SWT, r));                               \
        aH[mf] = *(const bf16x8*)(tH + byte);                                  \
        aL[mf] = *(const bf16x8*)(tL + byte);                                  \
      } }
#define LDB_P(KSG, J, D)                                                       \
    {                                                                          \
        size_t o = ((size_t)((2 * w + (J)) * BKS + (KSG)) * 64 + lane) * 8;    \
        D[0] = *(const bf16x8*)(bH + o);                                       \
        D[1] = *(const bf16x8*)(bL + o);                                       \
    }

    LDB_P(ks0, 0, Ba);
    #pragma unroll
    for (int ks = 0; ks < NKS; ++ks) {
        LDA_P(ks);
        LDB_P(ks0 + ks, 1, Bb);
        MFMA9(Ba, 0);
        if (ks + 1 < NKS) LDB_P(ks0 + ks + 1, 0, Ba);
        MFMA9(Bb, 1);
    }
#undef LDA_P
#undef LDB_P
}

// 4-float pack -> 8B hi-plane + 8B lo-plane
__device__ __forceinline__ void pack_write4(const float* ys, char* baseH, char* baseL, u32 byte) {
    u32x2 hv, lv;
    #pragma unroll
    for (int e = 0; e < 2; ++e) {
        float y0 = ys[2 * e], y1 = ys[2 * e + 1];
        u32 h = cvtpk2(y0, y1);
        hv[e] = h;
        float h0 = __builtin_bit_cast(float, h << 16);
        float h1 = __builtin_bit_cast(float, h & 0xFFFF0000u);
        lv[e] = cvtpk2(y0 - h0, y1 - h1);
    }
    *(u32x2*)(baseH + byte) = hv;
    *(u32x2*)(baseL + byte) = lv;
}

// ---------------- chunk0 pack (t 0..127 + fold 385..399), half-split ----------------
__device__ __forceinline__ float pack_c0(const float* wb, const float4* win4,
                                         const float* win, char* T,
                                         int f0, int rr, int cg) {
    const int fr = f0 + rr;
    const bool valid = fr < NFRAMES;
    const float* x = wb + (size_t)fr * FS;
    const float4* x4 = (const float4*)x;
    const u32 byte = (u32)rr * 272u + (u32)cg * 16u;
    float ps = 0.f;
    float cv, cxr, cwr;

    // ---- half A: t = 8cg .. 8cg+3 ----
    {
        float4 v0 = {0,0,0,0};
        if (valid) v0 = x4[2 * cg];
        ps += v0.x + v0.y + v0.z + v0.w;
        float4 w0 = win4[2 * cg];
        float xprev = v0.x;
        if (cg > 0 && valid) xprev = x[8 * cg - 1];
        float y0 = (v0.x - PRE * xprev) * w0.x;
        float y1 = (v0.y - PRE * v0.x) * w0.y;
        float y2 = (v0.z - PRE * v0.y) * w0.z;
        float y3 = (v0.w - PRE * v0.z) * w0.w;
        cv = v0.w;
        float r0 = 0.f, r1 = 0.f, r2 = 0.f, r3 = 0.f;
        cxr = 0.f; cwr = 0.f;
        if (cg >= 14) {                      // u = 512-t in 385..399
            const int u0 = 512 - 8 * cg;     // 400 (cg14) or 392 (cg15)
            float4 xr1 = {0,0,0,0};
            float xu0 = 0.f;
            if (valid) { xr1 = x4[u0 / 4 - 1]; if (u0 <= 399) xu0 = x[u0]; }
            ps += xr1.x + xr1.y + xr1.z + xr1.w;
            float4 wr1 = win4[u0 / 4 - 1];
            float wu0 = (u0 <= 399) ? win[u0] : 0.f;
            r0 = (xu0   - PRE * xr1.w) * wu0;
            r1 = (xr1.w - PRE * xr1.z) * wr1.w;
            r2 = (xr1.z - PRE * xr1.y) * wr1.z;
            r3 = (xr1.y - PRE * xr1.x) * wr1.y;
            cxr = xr1.x; cwr = wr1.x;
        }
        float s4[4] = {y0 + r0, y1 + r1, y2 + r2, y3 + r3};
        float d4[4] = {y0 - r0, y1 - r1, y2 - r2, y3 - r3};
        pack_write4(s4, T + C0_SH, T + C0_SL, byte);
        pack_write4(d4, T + C0_DH, T + C0_DL, byte);
    }
    // ---- half B: t = 8cg+4 .. 8cg+7 ----
    {
        float4 v1 = {0,0,0,0};
        if (valid) v1 = x4[2 * cg + 1];
        ps += v1.x + v1.y + v1.z + v1.w;
        float4 w1 = win4[2 * cg + 1];
        float y0 = (v1.x - PRE * cv)   * w1.x;
        float y1 = (v1.y - PRE * v1.x) * w1.y;
        float y2 = (v1.z - PRE * v1.y) * w1.z;
        float y3 = (v1.w - PRE * v1.z) * w1.w;
        float r0 = 0.f, r1 = 0.f, r2 = 0.f, r3 = 0.f;
        if (cg >= 14) {
            const int u0 = 512 - 8 * cg;
            float4 xr0 = {0,0,0,0};
            if (valid) xr0 = x4[u0 / 4 - 2];
            ps += xr0.x + xr0.y + xr0.z + xr0.w;
            float4 wr0 = win4[u0 / 4 - 2];
            r0 = (cxr   - PRE * xr0.w) * cwr;
            r1 = (xr0.w - PRE * xr0.z) * wr0.w;
            r2 = (xr0.z - PRE * xr0.y) * wr0.z;
            r3 = (xr0.y - PRE * xr0.x) * wr0.y;
        }
        float s4[4] = {y0 + r0, y1 + r1, y2 + r2, y3 + r3};
        float d4[4] = {y0 - r0, y1 - r1, y2 - r2, y3 - r3};
        pack_write4(s4, T + C0_SH, T + C0_SL, byte + 8);
        pack_write4(d4, T + C0_DH, T + C0_DL, byte + 8);
    }
    return ps;
}

// ---------------- chunk1 pack (t 128..255 + fold 256..384), half-split ----------------
__device__ __forceinline__ float pack_c1(const float* wb, const float4* win4,
                                         const float* win, char* T,
                                         int f0, int rr, int cg) {
    const int fr = f0 + rr;
    const bool valid = fr < NFRAMES;
    const float* x = wb + (size_t)fr * FS;
    const float4* x4 = (const float4*)x;
    const u32 byteS = (u32)rr * 320u + (((u32)cg * 16u) ^ ((((u32)rr >> 1) & 3u) << 4));
    const u32 byteD = (u32)rr * 272u + (u32)cg * 16u;
    const int u0 = 384 - 8 * cg;        // 264..384, all fold
    float ps = 0.f;
    float cv, cxr, cwr;

    // ---- half A: t = 128+8cg .. +3 ----
    {
        float4 v0 = {0,0,0,0};
        if (valid) v0 = x4[32 + 2 * cg];
        ps += v0.x + v0.y + v0.z + v0.w;
        float4 w0 = win4[32 + 2 * cg];
        float xprev = valid ? x[127 + 8 * cg] : 0.f;
        float y0 = (v0.x - PRE * xprev) * w0.x;
        float y1 = (v0.y - PRE * v0.x) * w0.y;
        float y2 = (v0.z - PRE * v0.y) * w0.z;
        float y3 = (v0.w - PRE * v0.z) * w0.w;
        cv = v0.w;
        float4 xr1 = {0,0,0,0};
        float xu0 = 0.f;
        if (valid) { xr1 = x4[u0 / 4 - 1]; xu0 = x[u0]; }
        ps += xr1.x + xr1.y + xr1.z + xr1.w;
        float4 wr1 = win4[u0 / 4 - 1];
        float wu0 = win[u0];
        float r0 = (xu0   - PRE * xr1.w) * wu0;
        float r1 = (xr1.w - PRE * xr1.z) * wr1.w;
        float r2 = (xr1.z - PRE * xr1.y) * wr1.z;
        float r3 = (xr1.y - PRE * xr1.x) * wr1.y;
        cxr = xr1.x; cwr = wr1.x;
        float s4[4] = {y0 + r0, y1 + r1, y2 + r2, y3 + r3};
        float d4[4] = {y0 - r0, y1 - r1, y2 - r2, y3 - r3};
        pack_write4(s4, T + C1_SH, T + C1_SL, byteS);
        pack_write4(d4, T + C1_DH, T + C1_DL, byteD);
    }
    // ---- half B: t = 128+8cg+4 .. +7 ----
    {
        float4 v1 = {0,0,0,0};
        if (valid) v1 = x4[33 + 2 * cg];
        ps += v1.x + v1.y + v1.z + v1.w;
        float4 w1 = win4[33 + 2 * cg];
        float y0 = (v1.x - PRE * cv)   * w1.x;
        float y1 = (v1.y - PRE * v1.x) * w1.y;
        float y2 = (v1.z - PRE * v1.y) * w1.z;
        float y3 = (v1.w - PRE * v1.z) * w1.w;
        float4 xr0 = {0,0,0,0};
        if (valid) xr0 = x4[u0 / 4 - 2];
        ps += xr0.x + xr0.y + xr0.z + xr0.w;
        float4 wr0 = win4[u0 / 4 - 2];
        float r0 = (cxr   - PRE * xr0.w) * cwr;
        float r1 = (xr0.w - PRE * xr0.z) * wr0.w;
        float r2 = (xr0.z - PRE * xr0.y) * wr0.z;
        float r3 = (xr0.y - PRE * xr0.x) * wr0.y;
        float s4[4] = {y0 + r0, y1 + r1, y2 + r2, y3 + r3};
        float d4[4] = {y0 - r0, y1 - r1, y2 - r2, y3 - r3};
        pack_write4(s4, T + C1_SH, T + C1_SL, byteS + 8);
        pack_write4(d4, T + C1_DH, T + C1_DL, byteD + 8);
    }
    return ps;
}

// ---------------- main fused kernel (512 threads / 8 waves, MT=48) ----------------
__global__ __launch_bounds__(512, 4) void fbank_mfma(
    const float* __restrict__ wave, const float* __restrict__ win,
    const u16* __restrict__ wsb, float* __restrict__ out) {
    __shared__ float smean[MT];
    __shared__ u16 stile[28416];       // 56,832 B tile buffer (power overlay fits)
    char* T = (char*)stile;

    const int tid = threadIdx.x, w = tid >> 6, lane = tid & 63;
    const int q = lane >> 4;           // frame sub-row within wave
    const int cg = lane & 15;          // col-group
    const int b = blockIdx.y;
    const int f0 = blockIdx.x * MT;
    const float* wb = wave + (size_t)b * TLEN;
    const float4* win4 = (const float4*)win;

    const int rrA = w * 4 + q;         // rows 0..31 (all waves)
    const int rrB = 32 + rrA;          // rows 32..47 (waves 0..3 only)

    // ---- P1b: chunk0 packs ----
    float psA = pack_c0(wb, win4, win, T, f0, rrA, cg);
    float psB = 0.f;
    if (w < 4) psB = pack_c0(wb, win4, win, T, f0, rrB, cg);
    __syncthreads();

    // ---- GEMM chunk0: RE ks 0..3 (A=s), IM ks 0..3 (A=d); wave w: bins 32w.. ----
    f32x4 accR[3][2], accI[3][2];
    #pragma unroll
    for (int mf = 0; mf < 3; ++mf)
        #pragma unroll
        for (int j = 0; j < 2; ++j) { accR[mf][j] = (f32x4)0.f; accI[mf][j] = (f32x4)0.f; }

    dft_pass3<272, 2, 4, RE_KS>(T + C0_SH, T + C0_SL, wsb + OFF_REH, wsb + OFF_REL, 0, w, lane, accR);
    dft_pass3<272, 2, 4, IM_KS>(T + C0_DH, T + C0_DL, wsb + OFF_IMH, wsb + OFF_IML, 0, w, lane, accI);
    __syncthreads();

    // ---- P1c: chunk1 packs + mean finalize + s tail ----
    psA += pack_c1(wb, win4, win, T, f0, rrA, cg);
    if (w < 4) psB += pack_c1(wb, win4, win, T, f0, rrB, cg);
    {
        float a = psA;
        #pragma unroll
        for (int o = 8; o; o >>= 1) a += __shfl_xor(a, o);
        if (cg == 0) smean[rrA] = a * (1.0f / FL);
    }
    if (w < 4) {
        float a = psB;
        #pragma unroll
        for (int o = 8; o; o >>= 1) a += __shfl_xor(a, o);
        if (cg == 0) smean[rrB] = a * (1.0f / FL);
    }
    // s tail: cols t=256..287 (units 16..19): only t=256 nonzero (x-only)
    if (w < 4 && lane < MT) {
        const int trr = lane;
        const int tfr = f0 + trr;
        float y256 = 0.f;
        if (w == 0 && tfr < NFRAMES) {
            const float* tx = wb + (size_t)tfr * FS;
            y256 = (tx[256] - PRE * tx[255]) * win[256];
        }
        float s4a[4] = {y256, 0.f, 0.f, 0.f};
        float s4b[4] = {0.f, 0.f, 0.f, 0.f};
        u32 byte = (u32)trr * 320u + ((((u32)(16 + w)) * 16u) ^ ((((u32)trr >> 1) & 3u) << 4));
        pack_write4(s4a, T + C1_SH, T + C1_SL, byte);
        pack_write4(s4b, T + C1_SH, T + C1_SL, byte + 8);
    }
    __syncthreads();

    // ---- GEMM chunk1: RE ks 4..8 (RS320 SWT1), IM ks 4..7 (RS272) ----
    dft_pass3<320, 1, 5, RE_KS>(T + C1_SH, T + C1_SL, wsb + OFF_REH, wsb + OFF_REL, 4, w, lane, accR);
    dft_pass3<272, 2, 4, IM_KS>(T + C1_DH, T + C1_DL, wsb + OFF_IMH, wsb + OFF_IML, 4, w, lane, accI);
    __syncthreads();

    // ---- power with mean correction -> LDS bf16 [48][256] (512-B stride) ----
    {
        const float* cs = (const float*)(wsb + OFF_CS);
        #pragma unroll
        for (int mf = 0; mf < 3; ++mf)
            #pragma unroll
            for (int j = 0; j < 2; ++j) {
                const u32 bin = (u32)(32 * w + j * 16 + cg);
                const float Cb = cs[bin], Sb = cs[256 + bin];
                #pragma unroll
                for (int r = 0; r < 4; ++r) {
                    u32 row = (u32)(mf * 16 + (q << 2) + r);
                    const float mcr = (1.0f - PRE) * smean[row];
                    float pR = accR[mf][j][r] - mcr * Cb;
                    float pI = accI[mf][j][r] - mcr * Sb;
                    float pw = pR * pR + pI * pI;
                    u32 byte = (row * 512u + bin * 2u) ^ ((row & 7u) << 4);
                    *(u16*)(T + byte) = f2bf(pw);
                }
            }
    }
    __syncthreads();

    // ---- mel GEMM (M=48, N=96 padded, K=256): 6 combos on waves 0..5 ----
    const u16* melb = wsb + OFF_MEL;
    if (w < 6) {
        const int mfm = w >> 1;            // row-group 0..2 (rows mfm*16..+15)
        const int nf0 = (w & 1) * 3;       // frag trio {0,1,2} or {3,4,5(pad)}
        f32x4 accM[3];
        #pragma unroll
        for (int j = 0; j < 3; ++j) accM[j] = (f32x4)0.f;
        for (int ks = 0; ks < 8; ++ks) {
            u32 row = (u32)(mfm * 16 + cg);
            u32 byte = (row * 512u + (u32)(ks * 32 + (q << 3)) * 2u) ^ ((row & 7u) << 4);
            bf16x8 aP = *(const bf16x8*)(T + byte);
            __builtin_amdgcn_s_setprio(1);
            #pragma unroll
            for (int j = 0; j < 3; ++j) {
                bf16x8 bM = *(const bf16x8*)(melb + ((size_t)((nf0 + j) * 8 + ks) * 64 + lane) * 8);
                accM[j] = __builtin_amdgcn_mfma_f32_16x16x32_bf16(aP, bM, accM[j], 0, 0, 0);
            }
            __builtin_amdgcn_s_setprio(0);
        }
        #pragma unroll
        for (int j = 0; j < 3; ++j) {
            const int m = (nf0 + j) * 16 + cg;
            #pragma unroll
            for (int r = 0; r < 4; ++r) {
                const int rowl = mfm * 16 + (q << 2) + r;
                const int ofr = f0 + rowl;
                if (ofr < NFRAMES && m < NM) {
                    float v = fmaxf(accM[j][r] + EPSF, EPSF);
                    out[((size_t)b * NFRAMES + ofr) * NM + m] = logf(v);
                }
            }
        }
    }
}

// ---------------- fallback (fp32 kernel, used if ws too small) ----------------
#define TFB 16
#define NB 256
__global__ __launch_bounds__(256, 3) void fbank_fallback(
    const float* __restrict__ wave, const float* __restrict__ win,
    const float* __restrict__ dftr, const float* __restrict__ dfti,
    const float* __restrict__ melw, float* __restrict__ out) {
    __shared__ float s_fr[TFB][PW];
    __shared__ float s_pw[TFB][NB + 1];
    const int tid = threadIdx.x, wv = tid >> 6, lane = tid & 63;
    const int fbase = blockIdx.x * TFB;
    #pragma unroll
    for (int j = 0; j < TFB / 4; ++j) {
        const int lf = wv * (TFB / 4) + j;
        const int gid = fbase + lf;
        const int bb = gid / NFRAMES;
        const int fr = gid - bb * NFRAMES;
        const float* x = wave + (size_t)bb * TLEN + (size_t)fr * FS;
        float s = 0.f;
        for (int i = lane; i < FL; i += 64) s += x[i];
        #pragma unroll
        for (int off = 32; off >= 1; off >>= 1) s += __shfl_xor(s, off);
        const float mean = s * (1.0f / FL);
        for (int i = lane; i < FL; i += 64) {
            const float xi = x[i];
            const float xm = (i == 0) ? xi : x[i - 1];
            s_fr[lf][i] = (xi - PRE * xm - (1.0f - PRE) * mean) * win[i];
        }
        for (int i = FL + lane; i < PW; i += 64) s_fr[lf][i] = 0.f;
    }
    __syncthreads();
    {
        const int bin = tid;
        const float4* dr4 = (const float4*)(dftr + (size_t)bin * PW);
        const float4* di4 = (const float4*)(dfti + (size_t)bin * PW);
        float accr[TFB], acci[TFB];
        #pragma unroll
        for (int f = 0; f < TFB; ++f) { accr[f] = 0.f; acci[f] = 0.f; }
        for (int k4 = 0; k4 < PW / 4; ++k4) {
            const float4 r = dr4[k4], im = di4[k4];
            #pragma unroll
            for (int f = 0; f < TFB; ++f) {
                const float4 fr = *(const float4*)&s_fr[f][k4 * 4];
                accr[f] += fr.x * r.x + fr.y * r.y + fr.z * r.z + fr.w * r.w;
                acci[f] += fr.x * im.x + fr.y * im.y + fr.z * im.z + fr.w * im.w;
            }
        }
        #pragma unroll
        for (int f = 0; f < TFB; ++f) s_pw[f][bin] = accr[f] * accr[f] + acci[f] * acci[f];
    }
    __syncthreads();
    for (int o = tid; o < TFB * NM; o += 256) {
        const int f = o / NM, m = o - f * NM;
        const float* wm = melw + (size_t)m * 257;
        float acc = 0.f;
        for (int k = 0; k < NB; ++k) acc += s_pw[f][k] * wm[k];
        out[(size_t)(fbase + f) * NM + m] = logf(fmaxf(acc + EPSF, EPSF));
    }
}

extern "C" void kernel_launch(void* const* d_in, const int* in_sizes, int n_in,
                              void* d_out, int out_size, void* d_ws, size_t ws_size,
                              hipStream_t stream) {
    const float* wave = (const float*)d_in[0];
    const float* win  = (const float*)d_in[1];
    const float* dftr = (const float*)d_in[2];
    const float* dfti = (const float*)d_in[3];
    const float* melw = (const float*)d_in[4];
    float* out = (float*)d_out;

    if (ws_size >= WS_NEED) {
        u16* wsb = (u16*)d_ws;
        const int prep_threads = 16 * RE_KS * 64 + 16 * IM_KS * 64 + 6 * 8 * 64;  // 20480
        prep_kernel<<<(prep_threads + 255) / 256, 256, 0, stream>>>(dftr, dfti, melw, wsb);
        prep_cs_kernel<<<128, 256, 0, stream>>>(dftr, dfti, win, wsb);   // 512 waves, 1/bin
        dim3 grid(NTILES, BATCH);
        fbank_mfma<<<grid, 512, 0, stream>>>(wave, win, wsb, out);
    } else {
        const int nblocks = (BATCH * NFRAMES) / TFB;
        fbank_fallback<<<nblocks, 256, 0, stream>>>(wave, win, dftr, dfti, melw, out);
    }
}

// Round 21
// 113.681 us; speedup vs baseline: 1.0951x; 1.0951x over previous
//
#include <hip/hip_runtime.h>
#include <math.h>

// Fbank via split-bf16 MFMA + real-DFT folding. R21 = R19 verbatim (revert of
// R20's setprio, which fenced live ranges over the 128-reg cap -> 48 MB spill,
// +11 us). R19: MT=48, (512,4), half-split packs, no spill, 113.8 us.

#define BATCH 32
#define TLEN 480000
#define NFRAMES 2998
#define FL 400
#define FS 160
#define PW 512
#define NM 80
#define MT 48                // frames per block
#define NTILES 63            // ceil(2998/48)
#define PRE 0.97f
#define EPSF 1e-6f

#define RE_KS 9              // K=288 (t 0..256 + pad)
#define IM_KS 8              // K=256 (t 0..255)
#define RE_U16 (16 * RE_KS * 64 * 8)   // 73728
#define IM_U16 (16 * IM_KS * 64 * 8)   // 65536
#define MEL_U16 (6 * 8 * 64 * 8)       // 24576
#define OFF_REH 0
#define OFF_REL RE_U16
#define OFF_IMH (2 * RE_U16)
#define OFF_IML (2 * RE_U16 + IM_U16)
#define OFF_MEL (2 * RE_U16 + 2 * IM_U16)
#define OFF_CS  (OFF_MEL + MEL_U16)          // u16 units; 512 floats follow
#define WS_NEED ((size_t)OFF_CS * 2 + 512 * 4)   // ~608 KB

// LDS tile byte offsets (48 rows). 272-B stride tiles: natural bank rotation,
// no XOR. 320-B chunk1 s-tile: SWT1 XOR (bits 4..5; +8 half-offset is bit 3).
#define C0_SH 0
#define C0_SL 13056
#define C0_DH 26112
#define C0_DL 39168          // chunk0 total 52,224 B
#define C1_SH 0
#define C1_SL 15360
#define C1_DH 30720
#define C1_DL 43776          // chunk1 total 56,832 B

typedef short bf16x8 __attribute__((ext_vector_type(8)));
typedef float f32x4 __attribute__((ext_vector_type(4)));
typedef unsigned int u32;
typedef unsigned short u16;
typedef u32 u32x2 __attribute__((ext_vector_type(2)));

__device__ __forceinline__ u16 f2bf(float f) {
    u32 u = __builtin_bit_cast(u32, f);
    return (u16)((u + 0x7FFFu + ((u >> 16) & 1u)) >> 16);
}
__device__ __forceinline__ float bf2f(u16 h) {
    u32 u = ((u32)h) << 16;
    return __builtin_bit_cast(float, u);
}
// packed bf16 convert: src0 -> low half, src1 -> high half
__device__ __forceinline__ u32 cvtpk2(float lo, float hi) {
    u32 r;
    asm("v_cvt_pk_bf16_f32 %0, %1, %2" : "=v"(r) : "v"(lo), "v"(hi));
    return r;
}

// ---------------- prep: folded B (cos/sin hi+lo) + mel ----------------
__global__ void prep_kernel(const float* __restrict__ dftr, const float* __restrict__ dfti,
                            const float* __restrict__ melw, u16* __restrict__ wsb) {
    int idx = blockIdx.x * 256 + threadIdx.x;
    if (idx < 16 * RE_KS * 64) {                       // 9216 Re groups
        int nf = idx / (RE_KS * 64);
        int rem = idx - nf * (RE_KS * 64);
        int ks = rem >> 6, l = rem & 63;
        int f = nf * 16 + (l & 15);
        int k = ks * 32 + ((l >> 4) << 3);
        u16* dh = wsb + OFF_REH + (size_t)idx * 8;
        u16* dl = wsb + OFF_REL + (size_t)idx * 8;
        #pragma unroll
        for (int e = 0; e < 8; ++e) {
            int kk = k + e;
            float x = (kk <= 256) ? dftr[(size_t)f * PW + kk] : 0.f;
            u16 h = f2bf(x);
            dh[e] = h;
            dl[e] = f2bf(x - bf2f(h));
        }
    } else if (idx < 16 * RE_KS * 64 + 16 * IM_KS * 64) {   // 8192 Im groups
        int j = idx - 16 * RE_KS * 64;
        int nf = j / (IM_KS * 64);
        int rem = j - nf * (IM_KS * 64);
        int ks = rem >> 6, l = rem & 63;
        int f = nf * 16 + (l & 15);
        int k = ks * 32 + ((l >> 4) << 3);
        u16* dh = wsb + OFF_IMH + (size_t)j * 8;
        u16* dl = wsb + OFF_IML + (size_t)j * 8;
        #pragma unroll
        for (int e = 0; e < 8; ++e) {
            float x = dfti[(size_t)f * PW + k + e];    // k+e <= 255
            u16 h = f2bf(x);
            dh[e] = h;
            dl[e] = f2bf(x - bf2f(h));
        }
    } else {                                            // mel groups
        int m = idx - (16 * RE_KS * 64 + 16 * IM_KS * 64);
        if (m < 6 * 8 * 64) {
            int nf = m / (8 * 64);
            int ks = (m >> 6) & 7, l = m & 63;
            int n = nf * 16 + (l & 15);
            int k = ks * 32 + ((l >> 4) << 3);
            u16* dst = wsb + OFF_MEL + (size_t)m * 8;
            #pragma unroll
            for (int e = 0; e < 8; ++e)
                dst[e] = (n < NM) ? f2bf(melw[(size_t)n * 257 + k + e]) : (u16)0;
        }
    }
}

// ---------------- prep C/S: one wave per bin (512 waves) ----------------
__global__ void prep_cs_kernel(const float* __restrict__ dftr, const float* __restrict__ dfti,
                               const float* __restrict__ win, u16* __restrict__ wsb) {
    const int gw = (blockIdx.x * 256 + threadIdx.x) >> 6;   // 0..511
    const int lane = threadIdx.x & 63;
    float* cs = (float*)(wsb + OFF_CS);
    float acc = 0.f;
    if (gw < 256) {
        const int f = gw;
        for (int t = lane; t <= 256; t += 64) {
            float wt = (t < FL) ? win[t] : 0.f;
            float wu = (t >= 1 && t < 256 && (512 - t) < FL) ? win[512 - t] : 0.f;
            acc += (wt + wu) * dftr[(size_t)f * PW + t];
        }
    } else {
        const int ff = gw - 256;
        for (int t = lane; t <= 255; t += 64) {
            float wt = (t < FL) ? win[t] : 0.f;
            float wu = (t >= 1 && (512 - t) < FL) ? win[512 - t] : 0.f;
            acc += (wt - wu) * dfti[(size_t)ff * PW + t];
        }
    }
    #pragma unroll
    for (int o = 32; o; o >>= 1) acc += __shfl_xor(acc, o);
    if (lane == 0) cs[gw] = acc;
}

// swizzle select: 0 -> (r&7)<<4 (512-B stride), 1 -> ((r>>1)&3)<<4 (320-B), 2 -> none (272-B)
__device__ __forceinline__ u32 swz(int SWT, u32 r) {
    return (SWT == 0) ? ((r & 7u) << 4) : (SWT == 1) ? (((r >> 1) & 3u) << 4) : 0u;
}

// 9 MFMA for one (bh,bl) ping-pong slot: 3 m-frags x 3 split-product terms
#define MFMA9(D, J)                                                                        \
    _Pragma("unroll")                                                                      \
    for (int mf = 0; mf < 3; ++mf) {                                                       \
        acc[mf][J] = __builtin_amdgcn_mfma_f32_16x16x32_bf16(aH[mf], D[0], acc[mf][J], 0, 0, 0); \
        acc[mf][J] = __builtin_amdgcn_mfma_f32_16x16x32_bf16(aL[mf], D[0], acc[mf][J], 0, 0, 0); \
        acc[mf][J] = __builtin_amdgcn_mfma_f32_16x16x32_bf16(aH[mf], D[1], acc[mf][J], 0, 0, 0); \
    }

// ---------------- DFT pass: 3 m-frags, 2 n-frags, B ping-pong prefetch ----------------
template<int RS, int SWT, int NKS, int BKS>
__device__ __forceinline__ void dft_pass3(
    const char* tH, const char* tL,
    const u16* __restrict__ bH, const u16* __restrict__ bL,
    int ks0, int w, int lane, f32x4 (&acc)[3][2]) {

    bf16x8 aH[3], aL[3], Ba[2], Bb[2];

#define LDA_P(KS)                                                              \
    { _Pragma("unroll")                                                        \
      for (int mf = 0; mf < 3; ++mf) {                                         \
        u32 r = (u32)(mf * 16 + (lane & 15));                                  \
        u32 off = (u32)((KS) * 64 + ((lane >> 4) << 4));                       \
        u32 byte = r * RS + (off ^ swz(SWT, r));                               \
        aH[mf] = *(const bf16x8*)(tH + byte);                                  \
        aL[mf] = *(const bf16x8*)(tL + byte);                                  \
      } }
#define LDB_P(KSG, J, D)                                                       \
    {                                                                          \
        size_t o = ((size_t)((2 * w + (J)) * BKS + (KSG)) * 64 + lane) * 8;    \
        D[0] = *(const bf16x8*)(bH + o);                                       \
        D[1] = *(const bf16x8*)(bL + o);                                       \
    }

    LDB_P(ks0, 0, Ba);
    #pragma unroll
    for (int ks = 0; ks < NKS; ++ks) {
        LDA_P(ks);
        LDB_P(ks0 + ks, 1, Bb);
        MFMA9(Ba, 0);
        if (ks + 1 < NKS) LDB_P(ks0 + ks + 1, 0, Ba);
        MFMA9(Bb, 1);
    }
#undef LDA_P
#undef LDB_P
}

// 4-float pack -> 8B hi-plane + 8B lo-plane
__device__ __forceinline__ void pack_write4(const float* ys, char* baseH, char* baseL, u32 byte) {
    u32x2 hv, lv;
    #pragma unroll
    for (int e = 0; e < 2; ++e) {
        float y0 = ys[2 * e], y1 = ys[2 * e + 1];
        u32 h = cvtpk2(y0, y1);
        hv[e] = h;
        float h0 = __builtin_bit_cast(float, h << 16);
        float h1 = __builtin_bit_cast(float, h & 0xFFFF0000u);
        lv[e] = cvtpk2(y0 - h0, y1 - h1);
    }
    *(u32x2*)(baseH + byte) = hv;
    *(u32x2*)(baseL + byte) = lv;
}

// ---------------- chunk0 pack (t 0..127 + fold 385..399), half-split ----------------
__device__ __forceinline__ float pack_c0(const float* wb, const float4* win4,
                                         const float* win, char* T,
                                         int f0, int rr, int cg) {
    const int fr = f0 + rr;
    const bool valid = fr < NFRAMES;
    const float* x = wb + (size_t)fr * FS;
    const float4* x4 = (const float4*)x;
    const u32 byte = (u32)rr * 272u + (u32)cg * 16u;
    float ps = 0.f;
    float cv, cxr, cwr;

    // ---- half A: t = 8cg .. 8cg+3 ----
    {
        float4 v0 = {0,0,0,0};
        if (valid) v0 = x4[2 * cg];
        ps += v0.x + v0.y + v0.z + v0.w;
        float4 w0 = win4[2 * cg];
        float xprev = v0.x;
        if (cg > 0 && valid) xprev = x[8 * cg - 1];
        float y0 = (v0.x - PRE * xprev) * w0.x;
        float y1 = (v0.y - PRE * v0.x) * w0.y;
        float y2 = (v0.z - PRE * v0.y) * w0.z;
        float y3 = (v0.w - PRE * v0.z) * w0.w;
        cv = v0.w;
        float r0 = 0.f, r1 = 0.f, r2 = 0.f, r3 = 0.f;
        cxr = 0.f; cwr = 0.f;
        if (cg >= 14) {                      // u = 512-t in 385..399
            const int u0 = 512 - 8 * cg;     // 400 (cg14) or 392 (cg15)
            float4 xr1 = {0,0,0,0};
            float xu0 = 0.f;
            if (valid) { xr1 = x4[u0 / 4 - 1]; if (u0 <= 399) xu0 = x[u0]; }
            ps += xr1.x + xr1.y + xr1.z + xr1.w;
            float4 wr1 = win4[u0 / 4 - 1];
            float wu0 = (u0 <= 399) ? win[u0] : 0.f;
            r0 = (xu0   - PRE * xr1.w) * wu0;
            r1 = (xr1.w - PRE * xr1.z) * wr1.w;
            r2 = (xr1.z - PRE * xr1.y) * wr1.z;
            r3 = (xr1.y - PRE * xr1.x) * wr1.y;
            cxr = xr1.x; cwr = wr1.x;
        }
        float s4[4] = {y0 + r0, y1 + r1, y2 + r2, y3 + r3};
        float d4[4] = {y0 - r0, y1 - r1, y2 - r2, y3 - r3};
        pack_write4(s4, T + C0_SH, T + C0_SL, byte);
        pack_write4(d4, T + C0_DH, T + C0_DL, byte);
    }
    // ---- half B: t = 8cg+4 .. 8cg+7 ----
    {
        float4 v1 = {0,0,0,0};
        if (valid) v1 = x4[2 * cg + 1];
        ps += v1.x + v1.y + v1.z + v1.w;
        float4 w1 = win4[2 * cg + 1];
        float y0 = (v1.x - PRE * cv)   * w1.x;
        float y1 = (v1.y - PRE * v1.x) * w1.y;
        float y2 = (v1.z - PRE * v1.y) * w1.z;
        float y3 = (v1.w - PRE * v1.z) * w1.w;
        float r0 = 0.f, r1 = 0.f, r2 = 0.f, r3 = 0.f;
        if (cg >= 14) {
            const int u0 = 512 - 8 * cg;
            float4 xr0 = {0,0,0,0};
            if (valid) xr0 = x4[u0 / 4 - 2];
            ps += xr0.x + xr0.y + xr0.z + xr0.w;
            float4 wr0 = win4[u0 / 4 - 2];
            r0 = (cxr   - PRE * xr0.w) * cwr;
            r1 = (xr0.w - PRE * xr0.z) * wr0.w;
            r2 = (xr0.z - PRE * xr0.y) * wr0.z;
            r3 = (xr0.y - PRE * xr0.x) * wr0.y;
        }
        float s4[4] = {y0 + r0, y1 + r1, y2 + r2, y3 + r3};
        float d4[4] = {y0 - r0, y1 - r1, y2 - r2, y3 - r3};
        pack_write4(s4, T + C0_SH, T + C0_SL, byte + 8);
        pack_write4(d4, T + C0_DH, T + C0_DL, byte + 8);
    }
    return ps;
}

// ---------------- chunk1 pack (t 128..255 + fold 256..384), half-split ----------------
__device__ __forceinline__ float pack_c1(const float* wb, const float4* win4,
                                         const float* win, char* T,
                                         int f0, int rr, int cg) {
    const int fr = f0 + rr;
    const bool valid = fr < NFRAMES;
    const float* x = wb + (size_t)fr * FS;
    const float4* x4 = (const float4*)x;
    const u32 byteS = (u32)rr * 320u + (((u32)cg * 16u) ^ ((((u32)rr >> 1) & 3u) << 4));
    const u32 byteD = (u32)rr * 272u + (u32)cg * 16u;
    const int u0 = 384 - 8 * cg;        // 264..384, all fold
    float ps = 0.f;
    float cv, cxr, cwr;

    // ---- half A: t = 128+8cg .. +3 ----
    {
        float4 v0 = {0,0,0,0};
        if (valid) v0 = x4[32 + 2 * cg];
        ps += v0.x + v0.y + v0.z + v0.w;
        float4 w0 = win4[32 + 2 * cg];
        float xprev = valid ? x[127 + 8 * cg] : 0.f;
        float y0 = (v0.x - PRE * xprev) * w0.x;
        float y1 = (v0.y - PRE * v0.x) * w0.y;
        float y2 = (v0.z - PRE * v0.y) * w0.z;
        float y3 = (v0.w - PRE * v0.z) * w0.w;
        cv = v0.w;
        float4 xr1 = {0,0,0,0};
        float xu0 = 0.f;
        if (valid) { xr1 = x4[u0 / 4 - 1]; xu0 = x[u0]; }
        ps += xr1.x + xr1.y + xr1.z + xr1.w;
        float4 wr1 = win4[u0 / 4 - 1];
        float wu0 = win[u0];
        float r0 = (xu0   - PRE * xr1.w) * wu0;
        float r1 = (xr1.w - PRE * xr1.z) * wr1.w;
        float r2 = (xr1.z - PRE * xr1.y) * wr1.z;
        float r3 = (xr1.y - PRE * xr1.x) * wr1.y;
        cxr = xr1.x; cwr = wr1.x;
        float s4[4] = {y0 + r0, y1 + r1, y2 + r2, y3 + r3};
        float d4[4] = {y0 - r0, y1 - r1, y2 - r2, y3 - r3};
        pack_write4(s4, T + C1_SH, T + C1_SL, byteS);
        pack_write4(d4, T + C1_DH, T + C1_DL, byteD);
    }
    // ---- half B: t = 128+8cg+4 .. +7 ----
    {
        float4 v1 = {0,0,0,0};
        if (valid) v1 = x4[33 + 2 * cg];
        ps += v1.x + v1.y + v1.z + v1.w;
        float4 w1 = win4[33 + 2 * cg];
        float y0 = (v1.x - PRE * cv)   * w1.x;
        float y1 = (v1.y - PRE * v1.x) * w1.y;
        float y2 = (v1.z - PRE * v1.y) * w1.z;
        float y3 = (v1.w - PRE * v1.z) * w1.w;
        float4 xr0 = {0,0,0,0};
        if (valid) xr0 = x4[u0 / 4 - 2];
        ps += xr0.x + xr0.y + xr0.z + xr0.w;
        float4 wr0 = win4[u0 / 4 - 2];
        float r0 = (cxr   - PRE * xr0.w) * cwr;
        float r1 = (xr0.w - PRE * xr0.z) * wr0.w;
        float r2 = (xr0.z - PRE * xr0.y) * wr0.z;
        float r3 = (xr0.y - PRE * xr0.x) * wr0.y;
        float s4[4] = {y0 + r0, y1 + r1, y2 + r2, y3 + r3};
        float d4[4] = {y0 - r0, y1 - r1, y2 - r2, y3 - r3};
        pack_write4(s4, T + C1_SH, T + C1_SL, byteS + 8);
        pack_write4(d4, T + C1_DH, T + C1_DL, byteD + 8);
    }
    return ps;
}

// ---------------- main fused kernel (512 threads / 8 waves, MT=48) ----------------
__global__ __launch_bounds__(512, 4) void fbank_mfma(
    const float* __restrict__ wave, const float* __restrict__ win,
    const u16* __restrict__ wsb, float* __restrict__ out) {
    __shared__ float smean[MT];
    __shared__ u16 stile[28416];       // 56,832 B tile buffer (power overlay fits)
    char* T = (char*)stile;

    const int tid = threadIdx.x, w = tid >> 6, lane = tid & 63;
    const int q = lane >> 4;           // frame sub-row within wave
    const int cg = lane & 15;          // col-group
    const int b = blockIdx.y;
    const int f0 = blockIdx.x * MT;
    const float* wb = wave + (size_t)b * TLEN;
    const float4* win4 = (const float4*)win;

    const int rrA = w * 4 + q;         // rows 0..31 (all waves)
    const int rrB = 32 + rrA;          // rows 32..47 (waves 0..3 only)

    // ---- P1b: chunk0 packs ----
    float psA = pack_c0(wb, win4, win, T, f0, rrA, cg);
    float psB = 0.f;
    if (w < 4) psB = pack_c0(wb, win4, win, T, f0, rrB, cg);
    __syncthreads();

    // ---- GEMM chunk0: RE ks 0..3 (A=s), IM ks 0..3 (A=d); wave w: bins 32w.. ----
    f32x4 accR[3][2], accI[3][2];
    #pragma unroll
    for (int mf = 0; mf < 3; ++mf)
        #pragma unroll
        for (int j = 0; j < 2; ++j) { accR[mf][j] = (f32x4)0.f; accI[mf][j] = (f32x4)0.f; }

    dft_pass3<272, 2, 4, RE_KS>(T + C0_SH, T + C0_SL, wsb + OFF_REH, wsb + OFF_REL, 0, w, lane, accR);
    dft_pass3<272, 2, 4, IM_KS>(T + C0_DH, T + C0_DL, wsb + OFF_IMH, wsb + OFF_IML, 0, w, lane, accI);
    __syncthreads();

    // ---- P1c: chunk1 packs + mean finalize + s tail ----
    psA += pack_c1(wb, win4, win, T, f0, rrA, cg);
    if (w < 4) psB += pack_c1(wb, win4, win, T, f0, rrB, cg);
    {
        float a = psA;
        #pragma unroll
        for (int o = 8; o; o >>= 1) a += __shfl_xor(a, o);
        if (cg == 0) smean[rrA] = a * (1.0f / FL);
    }
    if (w < 4) {
        float a = psB;
        #pragma unroll
        for (int o = 8; o; o >>= 1) a += __shfl_xor(a, o);
        if (cg == 0) smean[rrB] = a * (1.0f / FL);
    }
    // s tail: cols t=256..287 (units 16..19): only t=256 nonzero (x-only)
    if (w < 4 && lane < MT) {
        const int trr = lane;
        const int tfr = f0 + trr;
        float y256 = 0.f;
        if (w == 0 && tfr < NFRAMES) {
            const float* tx = wb + (size_t)tfr * FS;
            y256 = (tx[256] - PRE * tx[255]) * win[256];
        }
        float s4a[4] = {y256, 0.f, 0.f, 0.f};
        float s4b[4] = {0.f, 0.f, 0.f, 0.f};
        u32 byte = (u32)trr * 320u + ((((u32)(16 + w)) * 16u) ^ ((((u32)trr >> 1) & 3u) << 4));
        pack_write4(s4a, T + C1_SH, T + C1_SL, byte);
        pack_write4(s4b, T + C1_SH, T + C1_SL, byte + 8);
    }
    __syncthreads();

    // ---- GEMM chunk1: RE ks 4..8 (RS320 SWT1), IM ks 4..7 (RS272) ----
    dft_pass3<320, 1, 5, RE_KS>(T + C1_SH, T + C1_SL, wsb + OFF_REH, wsb + OFF_REL, 4, w, lane, accR);
    dft_pass3<272, 2, 4, IM_KS>(T + C1_DH, T + C1_DL, wsb + OFF_IMH, wsb + OFF_IML, 4, w, lane, accI);
    __syncthreads();

    // ---- power with mean correction -> LDS bf16 [48][256] (512-B stride) ----
    {
        const float* cs = (const float*)(wsb + OFF_CS);
        #pragma unroll
        for (int mf = 0; mf < 3; ++mf)
            #pragma unroll
            for (int j = 0; j < 2; ++j) {
                const u32 bin = (u32)(32 * w + j * 16 + cg);
                const float Cb = cs[bin], Sb = cs[256 + bin];
                #pragma unroll
                for (int r = 0; r < 4; ++r) {
                    u32 row = (u32)(mf * 16 + (q << 2) + r);
                    const float mcr = (1.0f - PRE) * smean[row];
                    float pR = accR[mf][j][r] - mcr * Cb;
                    float pI = accI[mf][j][r] - mcr * Sb;
                    float pw = pR * pR + pI * pI;
                    u32 byte = (row * 512u + bin * 2u) ^ ((row & 7u) << 4);
                    *(u16*)(T + byte) = f2bf(pw);
                }
            }
    }
    __syncthreads();

    // ---- mel GEMM (M=48, N=96 padded, K=256): 6 combos on waves 0..5 ----
    const u16* melb = wsb + OFF_MEL;
    if (w < 6) {
        const int mfm = w >> 1;            // row-group 0..2 (rows mfm*16..+15)
        const int nf0 = (w & 1) * 3;       // frag trio {0,1,2} or {3,4,5(pad)}
        f32x4 accM[3];
        #pragma unroll
        for (int j = 0; j < 3; ++j) accM[j] = (f32x4)0.f;
        for (int ks = 0; ks < 8; ++ks) {
            u32 row = (u32)(mfm * 16 + cg);
            u32 byte = (row * 512u + (u32)(ks * 32 + (q << 3)) * 2u) ^ ((row & 7u) << 4);
            bf16x8 aP = *(const bf16x8*)(T + byte);
            #pragma unroll
            for (int j = 0; j < 3; ++j) {
                bf16x8 bM = *(const bf16x8*)(melb + ((size_t)((nf0 + j) * 8 + ks) * 64 + lane) * 8);
                accM[j] = __builtin_amdgcn_mfma_f32_16x16x32_bf16(aP, bM, accM[j], 0, 0, 0);
            }
        }
        #pragma unroll
        for (int j = 0; j < 3; ++j) {
            const int m = (nf0 + j) * 16 + cg;
            #pragma unroll
            for (int r = 0; r < 4; ++r) {
                const int rowl = mfm * 16 + (q << 2) + r;
                const int ofr = f0 + rowl;
                if (ofr < NFRAMES && m < NM) {
                    float v = fmaxf(accM[j][r] + EPSF, EPSF);
                    out[((size_t)b * NFRAMES + ofr) * NM + m] = logf(v);
                }
            }
        }
    }
}

// ---------------- fallback (fp32 kernel, used if ws too small) ----------------
#define TFB 16
#define NB 256
__global__ __launch_bounds__(256, 3) void fbank_fallback(
    const float* __restrict__ wave, const float* __restrict__ win,
    const float* __restrict__ dftr, const float* __restrict__ dfti,
    const float* __restrict__ melw, float* __restrict__ out) {
    __shared__ float s_fr[TFB][PW];
    __shared__ float s_pw[TFB][NB + 1];
    const int tid = threadIdx.x, wv = tid >> 6, lane = tid & 63;
    const int fbase = blockIdx.x * TFB;
    #pragma unroll
    for (int j = 0; j < TFB / 4; ++j) {
        const int lf = wv * (TFB / 4) + j;
        const int gid = fbase + lf;
        const int bb = gid / NFRAMES;
        const int fr = gid - bb * NFRAMES;
        const float* x = wave + (size_t)bb * TLEN + (size_t)fr * FS;
        float s = 0.f;
        for (int i = lane; i < FL; i += 64) s += x[i];
        #pragma unroll
        for (int off = 32; off >= 1; off >>= 1) s += __shfl_xor(s, off);
        const float mean = s * (1.0f / FL);
        for (int i = lane; i < FL; i += 64) {
            const float xi = x[i];
            const float xm = (i == 0) ? xi : x[i - 1];
            s_fr[lf][i] = (xi - PRE * xm - (1.0f - PRE) * mean) * win[i];
        }
        for (int i = FL + lane; i < PW; i += 64) s_fr[lf][i] = 0.f;
    }
    __syncthreads();
    {
        const int bin = tid;
        const float4* dr4 = (const float4*)(dftr + (size_t)bin * PW);
        const float4* di4 = (const float4*)(dfti + (size_t)bin * PW);
        float accr[TFB], acci[TFB];
        #pragma unroll
        for (int f = 0; f < TFB; ++f) { accr[f] = 0.f; acci[f] = 0.f; }
        for (int k4 = 0; k4 < PW / 4; ++k4) {
            const float4 r = dr4[k4], im = di4[k4];
            #pragma unroll
            for (int f = 0; f < TFB; ++f) {
                const float4 fr = *(const float4*)&s_fr[f][k4 * 4];
                accr[f] += fr.x * r.x + fr.y * r.y + fr.z * r.z + fr.w * r.w;
                acci[f] += fr.x * im.x + fr.y * im.y + fr.z * im.z + fr.w * im.w;
            }
        }
        #pragma unroll
        for (int f = 0; f < TFB; ++f) s_pw[f][bin] = accr[f] * accr[f] + acci[f] * acci[f];
    }
    __syncthreads();
    for (int o = tid; o < TFB * NM; o += 256) {
        const int f = o / NM, m = o - f * NM;
        const float* wm = melw + (size_t)m * 257;
        float acc = 0.f;
        for (int k = 0; k < NB; ++k) acc += s_pw[f][k] * wm[k];
        out[(size_t)(fbase + f) * NM + m] = logf(fmaxf(acc + EPSF, EPSF));
    }
}

extern "C" void kernel_launch(void* const* d_in, const int* in_sizes, int n_in,
                              void* d_out, int out_size, void* d_ws, size_t ws_size,
                              hipStream_t stream) {
    const float* wave = (const float*)d_in[0];
    const float* win  = (const float*)d_in[1];
    const float* dftr = (const float*)d_in[2];
    const float* dfti = (const float*)d_in[3];
    const float* melw = (const float*)d_in[4];
    float* out = (float*)d_out;

    if (ws_size >= WS_NEED) {
        u16* wsb = (u16*)d_ws;
        const int prep_threads = 16 * RE_KS * 64 + 16 * IM_KS * 64 + 6 * 8 * 64;  // 20480
        prep_kernel<<<(prep_threads + 255) / 256, 256, 0, stream>>>(dftr, dfti, melw, wsb);
        prep_cs_kernel<<<128, 256, 0, stream>>>(dftr, dfti, win, wsb);   // 512 waves, 1/bin
        dim3 grid(NTILES, BATCH);
        fbank_mfma<<<grid, 512, 0, stream>>>(wave, win, wsb, out);
    } else {
        const int nblocks = (BATCH * NFRAMES) / TFB;
        fbank_fallback<<<nblocks, 256, 0, stream>>>(wave, win, dftr, dfti, melw, out);
    }
}

// Round 22
// 113.129 us; speedup vs baseline: 1.1004x; 1.0049x over previous
//
#include <hip/hip_runtime.h>
#include <math.h>

// Fbank via split-bf16 MFMA + real-DFT folding. R22 = R21 with a THREE-buffer
// B rotation in dft_pass3: B slots are issued 2 slots (~18 MFMA ~ 360 device
// cycles at 4 waves/SIMD) before use, vs 1 slot (~180 cyc) -- covering the
// ~200-cyc L2 hit latency that capped MfmaUtil at ~30%. +8 VGPR (72+48=120
// < 128 cap). Everything else identical to R21 (113.7 us, no spill).

#define BATCH 32
#define TLEN 480000
#define NFRAMES 2998
#define FL 400
#define FS 160
#define PW 512
#define NM 80
#define MT 48                // frames per block
#define NTILES 63            // ceil(2998/48)
#define PRE 0.97f
#define EPSF 1e-6f

#define RE_KS 9              // K=288 (t 0..256 + pad)
#define IM_KS 8              // K=256 (t 0..255)
#define RE_U16 (16 * RE_KS * 64 * 8)   // 73728
#define IM_U16 (16 * IM_KS * 64 * 8)   // 65536
#define MEL_U16 (6 * 8 * 64 * 8)       // 24576
#define OFF_REH 0
#define OFF_REL RE_U16
#define OFF_IMH (2 * RE_U16)
#define OFF_IML (2 * RE_U16 + IM_U16)
#define OFF_MEL (2 * RE_U16 + 2 * IM_U16)
#define OFF_CS  (OFF_MEL + MEL_U16)          // u16 units; 512 floats follow
#define WS_NEED ((size_t)OFF_CS * 2 + 512 * 4)   // ~608 KB

// LDS tile byte offsets (48 rows). 272-B stride tiles: natural bank rotation,
// no XOR. 320-B chunk1 s-tile: SWT1 XOR (bits 4..5; +8 half-offset is bit 3).
#define C0_SH 0
#define C0_SL 13056
#define C0_DH 26112
#define C0_DL 39168          // chunk0 total 52,224 B
#define C1_SH 0
#define C1_SL 15360
#define C1_DH 30720
#define C1_DL 43776          // chunk1 total 56,832 B

typedef short bf16x8 __attribute__((ext_vector_type(8)));
typedef float f32x4 __attribute__((ext_vector_type(4)));
typedef unsigned int u32;
typedef unsigned short u16;
typedef u32 u32x2 __attribute__((ext_vector_type(2)));

__device__ __forceinline__ u16 f2bf(float f) {
    u32 u = __builtin_bit_cast(u32, f);
    return (u16)((u + 0x7FFFu + ((u >> 16) & 1u)) >> 16);
}
__device__ __forceinline__ float bf2f(u16 h) {
    u32 u = ((u32)h) << 16;
    return __builtin_bit_cast(float, u);
}
// packed bf16 convert: src0 -> low half, src1 -> high half
__device__ __forceinline__ u32 cvtpk2(float lo, float hi) {
    u32 r;
    asm("v_cvt_pk_bf16_f32 %0, %1, %2" : "=v"(r) : "v"(lo), "v"(hi));
    return r;
}

// ---------------- prep: folded B (cos/sin hi+lo) + mel ----------------
__global__ void prep_kernel(const float* __restrict__ dftr, const float* __restrict__ dfti,
                            const float* __restrict__ melw, u16* __restrict__ wsb) {
    int idx = blockIdx.x * 256 + threadIdx.x;
    if (idx < 16 * RE_KS * 64) {                       // 9216 Re groups
        int nf = idx / (RE_KS * 64);
        int rem = idx - nf * (RE_KS * 64);
        int ks = rem >> 6, l = rem & 63;
        int f = nf * 16 + (l & 15);
        int k = ks * 32 + ((l >> 4) << 3);
        u16* dh = wsb + OFF_REH + (size_t)idx * 8;
        u16* dl = wsb + OFF_REL + (size_t)idx * 8;
        #pragma unroll
        for (int e = 0; e < 8; ++e) {
            int kk = k + e;
            float x = (kk <= 256) ? dftr[(size_t)f * PW + kk] : 0.f;
            u16 h = f2bf(x);
            dh[e] = h;
            dl[e] = f2bf(x - bf2f(h));
        }
    } else if (idx < 16 * RE_KS * 64 + 16 * IM_KS * 64) {   // 8192 Im groups
        int j = idx - 16 * RE_KS * 64;
        int nf = j / (IM_KS * 64);
        int rem = j - nf * (IM_KS * 64);
        int ks = rem >> 6, l = rem & 63;
        int f = nf * 16 + (l & 15);
        int k = ks * 32 + ((l >> 4) << 3);
        u16* dh = wsb + OFF_IMH + (size_t)j * 8;
        u16* dl = wsb + OFF_IML + (size_t)j * 8;
        #pragma unroll
        for (int e = 0; e < 8; ++e) {
            float x = dfti[(size_t)f * PW + k + e];    // k+e <= 255
            u16 h = f2bf(x);
            dh[e] = h;
            dl[e] = f2bf(x - bf2f(h));
        }
    } else {                                            // mel groups
        int m = idx - (16 * RE_KS * 64 + 16 * IM_KS * 64);
        if (m < 6 * 8 * 64) {
            int nf = m / (8 * 64);
            int ks = (m >> 6) & 7, l = m & 63;
            int n = nf * 16 + (l & 15);
            int k = ks * 32 + ((l >> 4) << 3);
            u16* dst = wsb + OFF_MEL + (size_t)m * 8;
            #pragma unroll
            for (int e = 0; e < 8; ++e)
                dst[e] = (n < NM) ? f2bf(melw[(size_t)n * 257 + k + e]) : (u16)0;
        }
    }
}

// ---------------- prep C/S: one wave per bin (512 waves) ----------------
__global__ void prep_cs_kernel(const float* __restrict__ dftr, const float* __restrict__ dfti,
                               const float* __restrict__ win, u16* __restrict__ wsb) {
    const int gw = (blockIdx.x * 256 + threadIdx.x) >> 6;   // 0..511
    const int lane = threadIdx.x & 63;
    float* cs = (float*)(wsb + OFF_CS);
    float acc = 0.f;
    if (gw < 256) {
        const int f = gw;
        for (int t = lane; t <= 256; t += 64) {
            float wt = (t < FL) ? win[t] : 0.f;
            float wu = (t >= 1 && t < 256 && (512 - t) < FL) ? win[512 - t] : 0.f;
            acc += (wt + wu) * dftr[(size_t)f * PW + t];
        }
    } else {
        const int ff = gw - 256;
        for (int t = lane; t <= 255; t += 64) {
            float wt = (t < FL) ? win[t] : 0.f;
            float wu = (t >= 1 && (512 - t) < FL) ? win[512 - t] : 0.f;
            acc += (wt - wu) * dfti[(size_t)ff * PW + t];
        }
    }
    #pragma unroll
    for (int o = 32; o; o >>= 1) acc += __shfl_xor(acc, o);
    if (lane == 0) cs[gw] = acc;
}

// swizzle select: 0 -> (r&7)<<4 (512-B stride), 1 -> ((r>>1)&3)<<4 (320-B), 2 -> none (272-B)
__device__ __forceinline__ u32 swz(int SWT, u32 r) {
    return (SWT == 0) ? ((r & 7u) << 4) : (SWT == 1) ? (((r >> 1) & 3u) << 4) : 0u;
}

// 9 MFMA for one (bh,bl) slot: 3 m-frags x 3 split-product terms
#define MFMA9(D, J)                                                                        \
    _Pragma("unroll")                                                                      \
    for (int mf = 0; mf < 3; ++mf) {                                                       \
        acc[mf][J] = __builtin_amdgcn_mfma_f32_16x16x32_bf16(aH[mf], D[0], acc[mf][J], 0, 0, 0); \
        acc[mf][J] = __builtin_amdgcn_mfma_f32_16x16x32_bf16(aL[mf], D[0], acc[mf][J], 0, 0, 0); \
        acc[mf][J] = __builtin_amdgcn_mfma_f32_16x16x32_bf16(aH[mf], D[1], acc[mf][J], 0, 0, 0); \
    }

// ---------------- DFT pass: 3 m-frags, 2 n-frags, 3-buffer B rotation ----------------
// B slot s (s = 2*ks_local + J) is issued 2 slots before its MFMA9 use.
template<int RS, int SWT, int NKS, int BKS>
__device__ __forceinline__ void dft_pass3(
    const char* tH, const char* tL,
    const u16* __restrict__ bH, const u16* __restrict__ bL,
    int ks0, int w, int lane, f32x4 (&acc)[3][2]) {

    bf16x8 aH[3], aL[3], B0[2], B1[2], B2[2];

#define LDA_P(KS)                                                              \
    { _Pragma("unroll")                                                        \
      for (int mf = 0; mf < 3; ++mf) {                                         \
        u32 r = (u32)(mf * 16 + (lane & 15));                                  \
        u32 off = (u32)((KS) * 64 + ((lane >> 4) << 4));                       \
        u32 byte = r * RS + (off ^ swz(SWT, r));                               \
        aH[mf] = *(const bf16x8*)(tH + byte);                                  \
        aL[mf] = *(const bf16x8*)(tL + byte);                                  \
      } }
#define LDB_S(S, D)                                                            \
    {                                                                          \
        size_t o = ((size_t)((2 * w + ((S) & 1)) * BKS + (ks0 + ((S) >> 1))) * 64 + lane) * 8; \
        D[0] = *(const bf16x8*)(bH + o);                                       \
        D[1] = *(const bf16x8*)(bL + o);                                       \
    }
// STEP(KS, P, Q, R): P holds slot 2KS, Q holds slot 2KS+1 (loaded earlier);
// R is free -> receives slot 2KS+2; P is free after its MFMA -> slot 2KS+3.
#define STEP(KS, P, Q, R)                                                      \
    {                                                                          \
        LDA_P(KS);                                                             \
        if constexpr (2 * (KS) + 2 < 2 * NKS) LDB_S(2 * (KS) + 2, R);          \
        MFMA9(P, 0);                                                           \
        if constexpr (2 * (KS) + 3 < 2 * NKS) LDB_S(2 * (KS) + 3, P);          \
        MFMA9(Q, 1);                                                           \
    }

    LDB_S(0, B0);
    LDB_S(1, B1);
    STEP(0, B0, B1, B2);
    if constexpr (NKS > 1) STEP(1, B2, B0, B1);
    if constexpr (NKS > 2) STEP(2, B1, B2, B0);
    if constexpr (NKS > 3) STEP(3, B0, B1, B2);
    if constexpr (NKS > 4) STEP(4, B2, B0, B1);
#undef LDA_P
#undef LDB_S
#undef STEP
}

// 4-float pack -> 8B hi-plane + 8B lo-plane
__device__ __forceinline__ void pack_write4(const float* ys, char* baseH, char* baseL, u32 byte) {
    u32x2 hv, lv;
    #pragma unroll
    for (int e = 0; e < 2; ++e) {
        float y0 = ys[2 * e], y1 = ys[2 * e + 1];
        u32 h = cvtpk2(y0, y1);
        hv[e] = h;
        float h0 = __builtin_bit_cast(float, h << 16);
        float h1 = __builtin_bit_cast(float, h & 0xFFFF0000u);
        lv[e] = cvtpk2(y0 - h0, y1 - h1);
    }
    *(u32x2*)(baseH + byte) = hv;
    *(u32x2*)(baseL + byte) = lv;
}

// ---------------- chunk0 pack (t 0..127 + fold 385..399), half-split ----------------
__device__ __forceinline__ float pack_c0(const float* wb, const float4* win4,
                                         const float* win, char* T,
                                         int f0, int rr, int cg) {
    const int fr = f0 + rr;
    const bool valid = fr < NFRAMES;
    const float* x = wb + (size_t)fr * FS;
    const float4* x4 = (const float4*)x;
    const u32 byte = (u32)rr * 272u + (u32)cg * 16u;
    float ps = 0.f;
    float cv, cxr, cwr;

    // ---- half A: t = 8cg .. 8cg+3 ----
    {
        float4 v0 = {0,0,0,0};
        if (valid) v0 = x4[2 * cg];
        ps += v0.x + v0.y + v0.z + v0.w;
        float4 w0 = win4[2 * cg];
        float xprev = v0.x;
        if (cg > 0 && valid) xprev = x[8 * cg - 1];
        float y0 = (v0.x - PRE * xprev) * w0.x;
        float y1 = (v0.y - PRE * v0.x) * w0.y;
        float y2 = (v0.z - PRE * v0.y) * w0.z;
        float y3 = (v0.w - PRE * v0.z) * w0.w;
        cv = v0.w;
        float r0 = 0.f, r1 = 0.f, r2 = 0.f, r3 = 0.f;
        cxr = 0.f; cwr = 0.f;
        if (cg >= 14) {                      // u = 512-t in 385..399
            const int u0 = 512 - 8 * cg;     // 400 (cg14) or 392 (cg15)
            float4 xr1 = {0,0,0,0};
            float xu0 = 0.f;
            if (valid) { xr1 = x4[u0 / 4 - 1]; if (u0 <= 399) xu0 = x[u0]; }
            ps += xr1.x + xr1.y + xr1.z + xr1.w;
            float4 wr1 = win4[u0 / 4 - 1];
            float wu0 = (u0 <= 399) ? win[u0] : 0.f;
            r0 = (xu0   - PRE * xr1.w) * wu0;
            r1 = (xr1.w - PRE * xr1.z) * wr1.w;
            r2 = (xr1.z - PRE * xr1.y) * wr1.z;
            r3 = (xr1.y - PRE * xr1.x) * wr1.y;
            cxr = xr1.x; cwr = wr1.x;
        }
        float s4[4] = {y0 + r0, y1 + r1, y2 + r2, y3 + r3};
        float d4[4] = {y0 - r0, y1 - r1, y2 - r2, y3 - r3};
        pack_write4(s4, T + C0_SH, T + C0_SL, byte);
        pack_write4(d4, T + C0_DH, T + C0_DL, byte);
    }
    // ---- half B: t = 8cg+4 .. 8cg+7 ----
    {
        float4 v1 = {0,0,0,0};
        if (valid) v1 = x4[2 * cg + 1];
        ps += v1.x + v1.y + v1.z + v1.w;
        float4 w1 = win4[2 * cg + 1];
        float y0 = (v1.x - PRE * cv)   * w1.x;
        float y1 = (v1.y - PRE * v1.x) * w1.y;
        float y2 = (v1.z - PRE * v1.y) * w1.z;
        float y3 = (v1.w - PRE * v1.z) * w1.w;
        float r0 = 0.f, r1 = 0.f, r2 = 0.f, r3 = 0.f;
        if (cg >= 14) {
            const int u0 = 512 - 8 * cg;
            float4 xr0 = {0,0,0,0};
            if (valid) xr0 = x4[u0 / 4 - 2];
            ps += xr0.x + xr0.y + xr0.z + xr0.w;
            float4 wr0 = win4[u0 / 4 - 2];
            r0 = (cxr   - PRE * xr0.w) * cwr;
            r1 = (xr0.w - PRE * xr0.z) * wr0.w;
            r2 = (xr0.z - PRE * xr0.y) * wr0.z;
            r3 = (xr0.y - PRE * xr0.x) * wr0.y;
        }
        float s4[4] = {y0 + r0, y1 + r1, y2 + r2, y3 + r3};
        float d4[4] = {y0 - r0, y1 - r1, y2 - r2, y3 - r3};
        pack_write4(s4, T + C0_SH, T + C0_SL, byte + 8);
        pack_write4(d4, T + C0_DH, T + C0_DL, byte + 8);
    }
    return ps;
}

// ---------------- chunk1 pack (t 128..255 + fold 256..384), half-split ----------------
__device__ __forceinline__ float pack_c1(const float* wb, const float4* win4,
                                         const float* win, char* T,
                                         int f0, int rr, int cg) {
    const int fr = f0 + rr;
    const bool valid = fr < NFRAMES;
    const float* x = wb + (size_t)fr * FS;
    const float4* x4 = (const float4*)x;
    const u32 byteS = (u32)rr * 320u + (((u32)cg * 16u) ^ ((((u32)rr >> 1) & 3u) << 4));
    const u32 byteD = (u32)rr * 272u + (u32)cg * 16u;
    const int u0 = 384 - 8 * cg;        // 264..384, all fold
    float ps = 0.f;
    float cv, cxr, cwr;

    // ---- half A: t = 128+8cg .. +3 ----
    {
        float4 v0 = {0,0,0,0};
        if (valid) v0 = x4[32 + 2 * cg];
        ps += v0.x + v0.y + v0.z + v0.w;
        float4 w0 = win4[32 + 2 * cg];
        float xprev = valid ? x[127 + 8 * cg] : 0.f;
        float y0 = (v0.x - PRE * xprev) * w0.x;
        float y1 = (v0.y - PRE * v0.x) * w0.y;
        float y2 = (v0.z - PRE * v0.y) * w0.z;
        float y3 = (v0.w - PRE * v0.z) * w0.w;
        cv = v0.w;
        float4 xr1 = {0,0,0,0};
        float xu0 = 0.f;
        if (valid) { xr1 = x4[u0 / 4 - 1]; xu0 = x[u0]; }
        ps += xr1.x + xr1.y + xr1.z + xr1.w;
        float4 wr1 = win4[u0 / 4 - 1];
        float wu0 = win[u0];
        float r0 = (xu0   - PRE * xr1.w) * wu0;
        float r1 = (xr1.w - PRE * xr1.z) * wr1.w;
        float r2 = (xr1.z - PRE * xr1.y) * wr1.z;
        float r3 = (xr1.y - PRE * xr1.x) * wr1.y;
        cxr = xr1.x; cwr = wr1.x;
        float s4[4] = {y0 + r0, y1 + r1, y2 + r2, y3 + r3};
        float d4[4] = {y0 - r0, y1 - r1, y2 - r2, y3 - r3};
        pack_write4(s4, T + C1_SH, T + C1_SL, byteS);
        pack_write4(d4, T + C1_DH, T + C1_DL, byteD);
    }
    // ---- half B: t = 128+8cg+4 .. +7 ----
    {
        float4 v1 = {0,0,0,0};
        if (valid) v1 = x4[33 + 2 * cg];
        ps += v1.x + v1.y + v1.z + v1.w;
        float4 w1 = win4[33 + 2 * cg];
        float y0 = (v1.x - PRE * cv)   * w1.x;
        float y1 = (v1.y - PRE * v1.x) * w1.y;
        float y2 = (v1.z - PRE * v1.y) * w1.z;
        float y3 = (v1.w - PRE * v1.z) * w1.w;
        float4 xr0 = {0,0,0,0};
        if (valid) xr0 = x4[u0 / 4 - 2];
        ps += xr0.x + xr0.y + xr0.z + xr0.w;
        float4 wr0 = win4[u0 / 4 - 2];
        float r0 = (cxr   - PRE * xr0.w) * cwr;
        float r1 = (xr0.w - PRE * xr0.z) * wr0.w;
        float r2 = (xr0.z - PRE * xr0.y) * wr0.z;
        float r3 = (xr0.y - PRE * xr0.x) * wr0.y;
        float s4[4] = {y0 + r0, y1 + r1, y2 + r2, y3 + r3};
        float d4[4] = {y0 - r0, y1 - r1, y2 - r2, y3 - r3};
        pack_write4(s4, T + C1_SH, T + C1_SL, byteS + 8);
        pack_write4(d4, T + C1_DH, T + C1_DL, byteD + 8);
    }
    return ps;
}

// ---------------- main fused kernel (512 threads / 8 waves, MT=48) ----------------
__global__ __launch_bounds__(512, 4) void fbank_mfma(
    const float* __restrict__ wave, const float* __restrict__ win,
    const u16* __restrict__ wsb, float* __restrict__ out) {
    __shared__ float smean[MT];
    __shared__ u16 stile[28416];       // 56,832 B tile buffer (power overlay fits)
    char* T = (char*)stile;

    const int tid = threadIdx.x, w = tid >> 6, lane = tid & 63;
    const int q = lane >> 4;           // frame sub-row within wave
    const int cg = lane & 15;          // col-group
    const int b = blockIdx.y;
    const int f0 = blockIdx.x * MT;
    const float* wb = wave + (size_t)b * TLEN;
    const float4* win4 = (const float4*)win;

    const int rrA = w * 4 + q;         // rows 0..31 (all waves)
    const int rrB = 32 + rrA;          // rows 32..47 (waves 0..3 only)

    // ---- P1b: chunk0 packs ----
    float psA = pack_c0(wb, win4, win, T, f0, rrA, cg);
    float psB = 0.f;
    if (w < 4) psB = pack_c0(wb, win4, win, T, f0, rrB, cg);
    __syncthreads();

    // ---- GEMM chunk0: RE ks 0..3 (A=s), IM ks 0..3 (A=d); wave w: bins 32w.. ----
    f32x4 accR[3][2], accI[3][2];
    #pragma unroll
    for (int mf = 0; mf < 3; ++mf)
        #pragma unroll
        for (int j = 0; j < 2; ++j) { accR[mf][j] = (f32x4)0.f; accI[mf][j] = (f32x4)0.f; }

    dft_pass3<272, 2, 4, RE_KS>(T + C0_SH, T + C0_SL, wsb + OFF_REH, wsb + OFF_REL, 0, w, lane, accR);
    dft_pass3<272, 2, 4, IM_KS>(T + C0_DH, T + C0_DL, wsb + OFF_IMH, wsb + OFF_IML, 0, w, lane, accI);
    __syncthreads();

    // ---- P1c: chunk1 packs + mean finalize + s tail ----
    psA += pack_c1(wb, win4, win, T, f0, rrA, cg);
    if (w < 4) psB += pack_c1(wb, win4, win, T, f0, rrB, cg);
    {
        float a = psA;
        #pragma unroll
        for (int o = 8; o; o >>= 1) a += __shfl_xor(a, o);
        if (cg == 0) smean[rrA] = a * (1.0f / FL);
    }
    if (w < 4) {
        float a = psB;
        #pragma unroll
        for (int o = 8; o; o >>= 1) a += __shfl_xor(a, o);
        if (cg == 0) smean[rrB] = a * (1.0f / FL);
    }
    // s tail: cols t=256..287 (units 16..19): only t=256 nonzero (x-only)
    if (w < 4 && lane < MT) {
        const int trr = lane;
        const int tfr = f0 + trr;
        float y256 = 0.f;
        if (w == 0 && tfr < NFRAMES) {
            const float* tx = wb + (size_t)tfr * FS;
            y256 = (tx[256] - PRE * tx[255]) * win[256];
        }
        float s4a[4] = {y256, 0.f, 0.f, 0.f};
        float s4b[4] = {0.f, 0.f, 0.f, 0.f};
        u32 byte = (u32)trr * 320u + ((((u32)(16 + w)) * 16u) ^ ((((u32)trr >> 1) & 3u) << 4));
        pack_write4(s4a, T + C1_SH, T + C1_SL, byte);
        pack_write4(s4b, T + C1_SH, T + C1_SL, byte + 8);
    }
    __syncthreads();

    // ---- GEMM chunk1: RE ks 4..8 (RS320 SWT1), IM ks 4..7 (RS272) ----
    dft_pass3<320, 1, 5, RE_KS>(T + C1_SH, T + C1_SL, wsb + OFF_REH, wsb + OFF_REL, 4, w, lane, accR);
    dft_pass3<272, 2, 4, IM_KS>(T + C1_DH, T + C1_DL, wsb + OFF_IMH, wsb + OFF_IML, 4, w, lane, accI);
    __syncthreads();

    // ---- power with mean correction -> LDS bf16 [48][256] (512-B stride) ----
    {
        const float* cs = (const float*)(wsb + OFF_CS);
        #pragma unroll
        for (int mf = 0; mf < 3; ++mf)
            #pragma unroll
            for (int j = 0; j < 2; ++j) {
                const u32 bin = (u32)(32 * w + j * 16 + cg);
                const float Cb = cs[bin], Sb = cs[256 + bin];
                #pragma unroll
                for (int r = 0; r < 4; ++r) {
                    u32 row = (u32)(mf * 16 + (q << 2) + r);
                    const float mcr = (1.0f - PRE) * smean[row];
                    float pR = accR[mf][j][r] - mcr * Cb;
                    float pI = accI[mf][j][r] - mcr * Sb;
                    float pw = pR * pR + pI * pI;
                    u32 byte = (row * 512u + bin * 2u) ^ ((row & 7u) << 4);
                    *(u16*)(T + byte) = f2bf(pw);
                }
            }
    }
    __syncthreads();

    // ---- mel GEMM (M=48, N=96 padded, K=256): 6 combos on waves 0..5 ----
    const u16* melb = wsb + OFF_MEL;
    if (w < 6) {
        const int mfm = w >> 1;            // row-group 0..2 (rows mfm*16..+15)
        const int nf0 = (w & 1) * 3;       // frag trio {0,1,2} or {3,4,5(pad)}
        f32x4 accM[3];
        #pragma unroll
        for (int j = 0; j < 3; ++j) accM[j] = (f32x4)0.f;
        for (int ks = 0; ks < 8; ++ks) {
            u32 row = (u32)(mfm * 16 + cg);
            u32 byte = (row * 512u + (u32)(ks * 32 + (q << 3)) * 2u) ^ ((row & 7u) << 4);
            bf16x8 aP = *(const bf16x8*)(T + byte);
            #pragma unroll
            for (int j = 0; j < 3; ++j) {
                bf16x8 bM = *(const bf16x8*)(melb + ((size_t)((nf0 + j) * 8 + ks) * 64 + lane) * 8);
                accM[j] = __builtin_amdgcn_mfma_f32_16x16x32_bf16(aP, bM, accM[j], 0, 0, 0);
            }
        }
        #pragma unroll
        for (int j = 0; j < 3; ++j) {
            const int m = (nf0 + j) * 16 + cg;
            #pragma unroll
            for (int r = 0; r < 4; ++r) {
                const int rowl = mfm * 16 + (q << 2) + r;
                const int ofr = f0 + rowl;
                if (ofr < NFRAMES && m < NM) {
                    float v = fmaxf(accM[j][r] + EPSF, EPSF);
                    out[((size_t)b * NFRAMES + ofr) * NM + m] = logf(v);
                }
            }
        }
    }
}

// ---------------- fallback (fp32 kernel, used if ws too small) ----------------
#define TFB 16
#define NB 256
__global__ __launch_bounds__(256, 3) void fbank_fallback(
    const float* __restrict__ wave, const float* __restrict__ win,
    const float* __restrict__ dftr, const float* __restrict__ dfti,
    const float* __restrict__ melw, float* __restrict__ out) {
    __shared__ float s_fr[TFB][PW];
    __shared__ float s_pw[TFB][NB + 1];
    const int tid = threadIdx.x, wv = tid >> 6, lane = tid & 63;
    const int fbase = blockIdx.x * TFB;
    #pragma unroll
    for (int j = 0; j < TFB / 4; ++j) {
        const int lf = wv * (TFB / 4) + j;
        const int gid = fbase + lf;
        const int bb = gid / NFRAMES;
        const int fr = gid - bb * NFRAMES;
        const float* x = wave + (size_t)bb * TLEN + (size_t)fr * FS;
        float s = 0.f;
        for (int i = lane; i < FL; i += 64) s += x[i];
        #pragma unroll
        for (int off = 32; off >= 1; off >>= 1) s += __shfl_xor(s, off);
        const float mean = s * (1.0f / FL);
        for (int i = lane; i < FL; i += 64) {
            const float xi = x[i];
            const float xm = (i == 0) ? xi : x[i - 1];
            s_fr[lf][i] = (xi - PRE * xm - (1.0f - PRE) * mean) * win[i];
        }
        for (int i = FL + lane; i < PW; i += 64) s_fr[lf][i] = 0.f;
    }
    __syncthreads();
    {
        const int bin = tid;
        const float4* dr4 = (const float4*)(dftr + (size_t)bin * PW);
        const float4* di4 = (const float4*)(dfti + (size_t)bin * PW);
        float accr[TFB], acci[TFB];
        #pragma unroll
        for (int f = 0; f < TFB; ++f) { accr[f] = 0.f; acci[f] = 0.f; }
        for (int k4 = 0; k4 < PW / 4; ++k4) {
            const float4 r = dr4[k4], im = di4[k4];
            #pragma unroll
            for (int f = 0; f < TFB; ++f) {
                const float4 fr = *(const float4*)&s_fr[f][k4 * 4];
                accr[f] += fr.x * r.x + fr.y * r.y + fr.z * r.z + fr.w * r.w;
                acci[f] += fr.x * im.x + fr.y * im.y + fr.z * im.z + fr.w * im.w;
            }
        }
        #pragma unroll
        for (int f = 0; f < TFB; ++f) s_pw[f][bin] = accr[f] * accr[f] + acci[f] * acci[f];
    }
    __syncthreads();
    for (int o = tid; o < TFB * NM; o += 256) {
        const int f = o / NM, m = o - f * NM;
        const float* wm = melw + (size_t)m * 257;
        float acc = 0.f;
        for (int k = 0; k < NB; ++k) acc += s_pw[f][k] * wm[k];
        out[(size_t)(fbase + f) * NM + m] = logf(fmaxf(acc + EPSF, EPSF));
    }
}

extern "C" void kernel_launch(void* const* d_in, const int* in_sizes, int n_in,
                              void* d_out, int out_size, void* d_ws, size_t ws_size,
                              hipStream_t stream) {
    const float* wave = (const float*)d_in[0];
    const float* win  = (const float*)d_in[1];
    const float* dftr = (const float*)d_in[2];
    const float* dfti = (const float*)d_in[3];
    const float* melw = (const float*)d_in[4];
    float* out = (float*)d_out;

    if (ws_size >= WS_NEED) {
        u16* wsb = (u16*)d_ws;
        const int prep_threads = 16 * RE_KS * 64 + 16 * IM_KS * 64 + 6 * 8 * 64;  // 20480
        prep_kernel<<<(prep_threads + 255) / 256, 256, 0, stream>>>(dftr, dfti, melw, wsb);
        prep_cs_kernel<<<128, 256, 0, stream>>>(dftr, dfti, win, wsb);   // 512 waves, 1/bin
        dim3 grid(NTILES, BATCH);
        fbank_mfma<<<grid, 512, 0, stream>>>(wave, win, wsb, out);
    } else {
        const int nblocks = (BATCH * NFRAMES) / TFB;
        fbank_fallback<<<nblocks, 256, 0, stream>>>(wave, win, dftr, dfti, melw, out);
    }
}